// Round 2
// baseline (97.566 us; speedup 1.0000x reference)
//
#include <hip/hip_runtime.h>

#define BPB 32                  // blocks per batch
#define TPB 256                 // threads per block
#define NB  32                  // batches (asserted from in_sizes at launch)
#define TOTAL_BLOCKS (BPB * NB) // 1024, divides 2^32 -> poison-proof modulo trigger

__device__ inline void quat_to_rot_dev(float x, float y, float z, float w, float R[3][3]) {
    float inv = rsqrtf(x * x + y * y + z * z + w * w);
    x *= inv; y *= inv; z *= inv; w *= inv;
    const float xx = x * x, yy = y * y, zz = z * z;
    const float xy = x * y, xz = x * z, yz = y * z;
    const float wx = w * x, wy = w * y, wz = w * z;
    R[0][0] = 1.f - 2.f * (yy + zz); R[0][1] = 2.f * (xy - wz);       R[0][2] = 2.f * (xz + wy);
    R[1][0] = 2.f * (xy + wz);       R[1][1] = 1.f - 2.f * (xx + zz); R[1][2] = 2.f * (yz - wx);
    R[2][0] = 2.f * (xz - wy);       R[2][1] = 2.f * (yz + wx);       R[2][2] = 1.f - 2.f * (xx + yy);
}

__global__ __launch_bounds__(TPB) void fused_kernel(
        const float* __restrict__ points,
        const float* __restrict__ predquat,
        const float* __restrict__ gtquat,
        float* __restrict__ partials,       // [NB*BPB*6] in d_ws
        unsigned int* __restrict__ counter, // 1 uint after partials in d_ws
        float* __restrict__ out, int N, int B) {
    const int bid = blockIdx.x;
    const int b   = bid >> 5;     // / BPB
    const int blk = bid & (BPB - 1);

    // ---- phase 1: per-block partial second moments ----
    const int n4 = N >> 2;
    const float4* __restrict__ px = (const float4*)(points + (size_t)b * 3 * N);
    const float4* __restrict__ py = px + n4;
    const float4* __restrict__ pz = px + 2 * n4;

    float sxx = 0.f, syy = 0.f, szz = 0.f, sxy = 0.f, sxz = 0.f, syz = 0.f;
    const int stride = BPB * TPB;
    for (int i = blk * TPB + threadIdx.x; i < n4; i += stride) {
        float4 x = px[i];
        float4 y = py[i];
        float4 z = pz[i];
        sxx += x.x * x.x + x.y * x.y + x.z * x.z + x.w * x.w;
        syy += y.x * y.x + y.y * y.y + y.z * y.z + y.w * y.w;
        szz += z.x * z.x + z.y * z.y + z.z * z.z + z.w * z.w;
        sxy += x.x * y.x + x.y * y.y + x.z * y.z + x.w * y.w;
        sxz += x.x * z.x + x.y * z.y + x.z * z.z + x.w * z.w;
        syz += y.x * z.x + y.y * z.y + y.z * z.z + y.w * z.w;
    }

    for (int off = 32; off > 0; off >>= 1) {
        sxx += __shfl_down(sxx, off);
        syy += __shfl_down(syy, off);
        szz += __shfl_down(szz, off);
        sxy += __shfl_down(sxy, off);
        sxz += __shfl_down(sxz, off);
        syz += __shfl_down(syz, off);
    }

    __shared__ float red[TPB / 64][6];
    const int wave = threadIdx.x >> 6;
    const int lane = threadIdx.x & 63;
    if (lane == 0) {
        red[wave][0] = sxx; red[wave][1] = syy; red[wave][2] = szz;
        red[wave][3] = sxy; red[wave][4] = sxz; red[wave][5] = syz;
    }
    __syncthreads();
    if (threadIdx.x < 6) {
        float s = 0.f;
        for (int w = 0; w < TPB / 64; ++w) s += red[w][threadIdx.x];
        partials[((size_t)bid) * 6 + threadIdx.x] = s;
    }

    // ---- release partials, bump grid counter ----
    __threadfence();     // device-scope: make this block's partial visible
    __syncthreads();     // order all threads' stores+fences before thread 0's RMW
    __shared__ int amLast;
    if (threadIdx.x == 0) {
        unsigned int old = atomicAdd(counter, 1u);
        // poison-proof trigger: fires for exactly one block per call regardless
        // of counter's initial value; 2^32 % TOTAL_BLOCKS == 0 so wrap is safe.
        amLast = ((old & (TOTAL_BLOCKS - 1)) == (TOTAL_BLOCKS - 1));
    }
    __syncthreads();
    if (!amLast) return;

    // ---- phase 2 (one block): reduce partials, chamfer ----
    __threadfence();
    __shared__ float smom[NB][6];
    const int t = threadIdx.x;
    if (t < NB * 6) {
        const int bb = t / 6, k = t % 6;
        float s = 0.f;
        for (int j = 0; j < BPB; ++j)
            s += __hip_atomic_load(&partials[((size_t)bb * BPB + j) * 6 + k],
                                   __ATOMIC_ACQUIRE, __HIP_MEMORY_SCOPE_AGENT);
        smom[bb][k] = s;
    }
    __syncthreads();

    float val = 0.f;
    if (t < B) {
        const float* m = smom[t];
        const float M[3][3] = {{m[0], m[3], m[4]},
                               {m[3], m[1], m[5]},
                               {m[4], m[5], m[2]}};
        float P[3][3], G[3][3];
        quat_to_rot_dev(predquat[4 * t], predquat[4 * t + 1], predquat[4 * t + 2], predquat[4 * t + 3], P);
        quat_to_rot_dev(gtquat[4 * t], gtquat[4 * t + 1], gtquat[4 * t + 2], gtquat[4 * t + 3], G);

        float gg[3];
        for (int j = 0; j < 3; ++j) {
            const float t0 = G[j][0] * M[0][0] + G[j][1] * M[1][0] + G[j][2] * M[2][0];
            const float t1 = G[j][0] * M[0][1] + G[j][1] * M[1][1] + G[j][2] * M[2][1];
            const float t2 = G[j][0] * M[0][2] + G[j][1] * M[1][2] + G[j][2] * M[2][2];
            gg[j] = t0 * G[j][0] + t1 * G[j][1] + t2 * G[j][2];
        }
        float pp[3], cr[3][3];
        for (int i = 0; i < 3; ++i) {
            const float t0 = P[i][0] * M[0][0] + P[i][1] * M[1][0] + P[i][2] * M[2][0];
            const float t1 = P[i][0] * M[0][1] + P[i][1] * M[1][1] + P[i][2] * M[2][1];
            const float t2 = P[i][0] * M[0][2] + P[i][1] * M[1][2] + P[i][2] * M[2][2];
            pp[i] = t0 * P[i][0] + t1 * P[i][1] + t2 * P[i][2];
            for (int j = 0; j < 3; ++j)
                cr[i][j] = t0 * G[j][0] + t1 * G[j][1] + t2 * G[j][2];
        }
        float acc = 0.f;
        for (int j = 0; j < 3; ++j) {
            const float d0 = gg[j] + pp[0] - 2.f * cr[0][j];
            const float d1 = gg[j] + pp[1] - 2.f * cr[1][j];
            const float d2 = gg[j] + pp[2] - 2.f * cr[2][j];
            acc += fminf(d0, fminf(d1, d2));
        }
        val = acc / 3.f;
    }
    // lanes B..63 of wave 0 carry 0; waves 1..3 exited via !amLast path? No —
    // all threads of the last block are here; only wave 0 reduces/writes.
    if (t < 64) {
        for (int off = 32; off > 0; off >>= 1) val += __shfl_down(val, off);
        if (t == 0) out[0] = val / (float)B;
    }
}

extern "C" void kernel_launch(void* const* d_in, const int* in_sizes, int n_in,
                              void* d_out, int out_size, void* d_ws, size_t ws_size,
                              hipStream_t stream) {
    const float* predquat = (const float*)d_in[0];
    const float* gtquat   = (const float*)d_in[1];
    const float* points   = (const float*)d_in[2];
    float* out = (float*)d_out;

    float* partials = (float*)d_ws;                         // NB*BPB*6 floats = 24 KB
    unsigned int* counter = (unsigned int*)(partials + (size_t)NB * BPB * 6);

    const int B = in_sizes[0] / 4;           // 32
    const int N = in_sizes[2] / (B * 3);     // 262144

    fused_kernel<<<TOTAL_BLOCKS, TPB, 0, stream>>>(points, predquat, gtquat,
                                                   partials, counter, out, N, B);
}

// Round 3
// 26.341 us; speedup vs baseline: 3.7040x; 3.7040x over previous
//
#include <hip/hip_runtime.h>

#define BPB 64      // blocks per batch
#define TPB 256     // threads per block

__global__ __launch_bounds__(TPB) void moments_kernel(
        const float* __restrict__ points, float* __restrict__ partials, int N) {
    const int b = blockIdx.y;
    const int n4 = N >> 2;
    const float4* __restrict__ px = (const float4*)(points + (size_t)b * 3 * N);
    const float4* __restrict__ py = px + n4;
    const float4* __restrict__ pz = px + 2 * n4;

    float sxx = 0.f, syy = 0.f, szz = 0.f, sxy = 0.f, sxz = 0.f, syz = 0.f;
    const int stride = BPB * TPB;
    #pragma unroll 2
    for (int i = blockIdx.x * TPB + threadIdx.x; i < n4; i += stride) {
        float4 x = px[i];
        float4 y = py[i];
        float4 z = pz[i];
        sxx += x.x * x.x + x.y * x.y + x.z * x.z + x.w * x.w;
        syy += y.x * y.x + y.y * y.y + y.z * y.z + y.w * y.w;
        szz += z.x * z.x + z.y * z.y + z.z * z.z + z.w * z.w;
        sxy += x.x * y.x + x.y * y.y + x.z * y.z + x.w * y.w;
        sxz += x.x * z.x + x.y * z.y + x.z * z.z + x.w * z.w;
        syz += y.x * z.x + y.y * z.y + y.z * z.z + y.w * z.w;
    }

    // wave (64-lane) butterfly reduction
    for (int off = 32; off > 0; off >>= 1) {
        sxx += __shfl_down(sxx, off);
        syy += __shfl_down(syy, off);
        szz += __shfl_down(szz, off);
        sxy += __shfl_down(sxy, off);
        sxz += __shfl_down(sxz, off);
        syz += __shfl_down(syz, off);
    }

    __shared__ float red[TPB / 64][6];
    const int wave = threadIdx.x >> 6;
    const int lane = threadIdx.x & 63;
    if (lane == 0) {
        red[wave][0] = sxx; red[wave][1] = syy; red[wave][2] = szz;
        red[wave][3] = sxy; red[wave][4] = sxz; red[wave][5] = syz;
    }
    __syncthreads();
    if (threadIdx.x < 6) {
        float s = 0.f;
        for (int w = 0; w < TPB / 64; ++w) s += red[w][threadIdx.x];
        partials[((size_t)b * BPB + blockIdx.x) * 6 + threadIdx.x] = s;
    }
}

__device__ inline void quat_to_rot_dev(float x, float y, float z, float w, float R[3][3]) {
    float inv = rsqrtf(x * x + y * y + z * z + w * w);
    x *= inv; y *= inv; z *= inv; w *= inv;
    const float xx = x * x, yy = y * y, zz = z * z;
    const float xy = x * y, xz = x * z, yz = y * z;
    const float wx = w * x, wy = w * y, wz = w * z;
    R[0][0] = 1.f - 2.f * (yy + zz); R[0][1] = 2.f * (xy - wz);       R[0][2] = 2.f * (xz + wy);
    R[1][0] = 2.f * (xy + wz);       R[1][1] = 1.f - 2.f * (xx + zz); R[1][2] = 2.f * (yz - wx);
    R[2][0] = 2.f * (xz - wy);       R[2][1] = 2.f * (yz + wx);       R[2][2] = 1.f - 2.f * (xx + yy);
}

__global__ __launch_bounds__(256) void finalize_kernel(
        const float* __restrict__ predquat,
        const float* __restrict__ gtquat,
        const float* __restrict__ partials,
        float* __restrict__ out, int B) {
    __shared__ float smom[32][6];
    const int t = threadIdx.x;
    // stage 1: 192 lanes each reduce one (batch, component) pair over BPB blocks
    if (t < B * 6) {
        const int bb = t / 6, k = t % 6;
        float s = 0.f;
        #pragma unroll 8
        for (int j = 0; j < BPB; ++j)
            s += partials[((size_t)bb * BPB + j) * 6 + k];
        smom[bb][k] = s;
    }
    __syncthreads();
    if (t >= 64) return;

    float val = 0.f;
    if (t < B) {
        const float* m = smom[t];
        const float M[3][3] = {{m[0], m[3], m[4]},
                               {m[3], m[1], m[5]},
                               {m[4], m[5], m[2]}};
        float P[3][3], G[3][3];
        quat_to_rot_dev(predquat[4 * t], predquat[4 * t + 1], predquat[4 * t + 2], predquat[4 * t + 3], P);
        quat_to_rot_dev(gtquat[4 * t], gtquat[4 * t + 1], gtquat[4 * t + 2], gtquat[4 * t + 3], G);

        // gg[j] = G_j M G_j^T
        float gg[3];
        for (int j = 0; j < 3; ++j) {
            const float t0 = G[j][0] * M[0][0] + G[j][1] * M[1][0] + G[j][2] * M[2][0];
            const float t1 = G[j][0] * M[0][1] + G[j][1] * M[1][1] + G[j][2] * M[2][1];
            const float t2 = G[j][0] * M[0][2] + G[j][1] * M[1][2] + G[j][2] * M[2][2];
            gg[j] = t0 * G[j][0] + t1 * G[j][1] + t2 * G[j][2];
        }
        // pp[i] = P_i M P_i^T ; cr[i][j] = P_i M G_j^T
        float pp[3], cr[3][3];
        for (int i = 0; i < 3; ++i) {
            const float t0 = P[i][0] * M[0][0] + P[i][1] * M[1][0] + P[i][2] * M[2][0];
            const float t1 = P[i][0] * M[0][1] + P[i][1] * M[1][1] + P[i][2] * M[2][1];
            const float t2 = P[i][0] * M[0][2] + P[i][1] * M[1][2] + P[i][2] * M[2][2];
            pp[i] = t0 * P[i][0] + t1 * P[i][1] + t2 * P[i][2];
            for (int j = 0; j < 3; ++j)
                cr[i][j] = t0 * G[j][0] + t1 * G[j][1] + t2 * G[j][2];
        }
        float acc = 0.f;
        for (int j = 0; j < 3; ++j) {
            const float d0 = gg[j] + pp[0] - 2.f * cr[0][j];
            const float d1 = gg[j] + pp[1] - 2.f * cr[1][j];
            const float d2 = gg[j] + pp[2] - 2.f * cr[2][j];
            acc += fminf(d0, fminf(d1, d2));
        }
        val = acc / 3.f;
    }
    // wave reduce sum across 64 lanes (wave 0 only; others returned)
    for (int off = 32; off > 0; off >>= 1) val += __shfl_down(val, off);
    if (t == 0) out[0] = val / (float)B;
}

extern "C" void kernel_launch(void* const* d_in, const int* in_sizes, int n_in,
                              void* d_out, int out_size, void* d_ws, size_t ws_size,
                              hipStream_t stream) {
    const float* predquat = (const float*)d_in[0];
    const float* gtquat   = (const float*)d_in[1];
    const float* points   = (const float*)d_in[2];
    float* out = (float*)d_out;
    float* partials = (float*)d_ws;  // B * BPB * 6 floats = 48 KB

    const int B = in_sizes[0] / 4;           // 32
    const int N = in_sizes[2] / (B * 3);     // 262144

    dim3 grid(BPB, B);
    moments_kernel<<<grid, TPB, 0, stream>>>(points, partials, N);
    finalize_kernel<<<1, 256, 0, stream>>>(predquat, gtquat, partials, out, B);
}

// Round 5
// 21.636 us; speedup vs baseline: 4.5095x; 1.2175x over previous
//
#include <hip/hip_runtime.h>

#define BPB 32      // blocks per batch
#define TPB 256     // threads per block

typedef float vf4 __attribute__((ext_vector_type(4)));  // native vec: OK for nontemporal builtin

// Partials layout: [b][6][BPB] so the finalize stage-1 reads are contiguous.

template <int ITERS>
__global__ __launch_bounds__(TPB) void moments_kernel(
        const float* __restrict__ points, float* __restrict__ partials, int N) {
    const int b = blockIdx.y;
    const int n4 = N >> 2;
    const vf4* __restrict__ px = (const vf4*)(points + (size_t)b * 3 * N);
    const vf4* __restrict__ py = px + n4;
    const vf4* __restrict__ pz = px + 2 * n4;

    float sxx = 0.f, syy = 0.f, szz = 0.f, sxy = 0.f, sxz = 0.f, syz = 0.f;
    const int base = blockIdx.x * TPB + threadIdx.x;
    const int stride = BPB * TPB;

    if constexpr (ITERS > 0) {
        // exact trip count known: fully unrolled, no bounds check
        #pragma unroll
        for (int it = 0; it < ITERS; ++it) {
            const int i = base + it * stride;
            const vf4 x = __builtin_nontemporal_load(&px[i]);
            const vf4 y = __builtin_nontemporal_load(&py[i]);
            const vf4 z = __builtin_nontemporal_load(&pz[i]);
            sxx += x.x * x.x + x.y * x.y + x.z * x.z + x.w * x.w;
            syy += y.x * y.x + y.y * y.y + y.z * y.z + y.w * y.w;
            szz += z.x * z.x + z.y * z.y + z.z * z.z + z.w * z.w;
            sxy += x.x * y.x + x.y * y.y + x.z * y.z + x.w * y.w;
            sxz += x.x * z.x + x.y * z.y + x.z * z.z + x.w * z.w;
            syz += y.x * z.x + y.y * z.y + y.z * z.z + y.w * z.w;
        }
    } else {
        for (int i = base; i < n4; i += stride) {
            const vf4 x = px[i];
            const vf4 y = py[i];
            const vf4 z = pz[i];
            sxx += x.x * x.x + x.y * x.y + x.z * x.z + x.w * x.w;
            syy += y.x * y.x + y.y * y.y + y.z * y.z + y.w * y.w;
            szz += z.x * z.x + z.y * z.y + z.z * z.z + z.w * z.w;
            sxy += x.x * y.x + x.y * y.y + x.z * y.z + x.w * y.w;
            sxz += x.x * z.x + x.y * z.y + x.z * z.z + x.w * z.w;
            syz += y.x * z.x + y.y * z.y + y.z * z.z + y.w * z.w;
        }
    }

    // wave (64-lane) butterfly reduction
    for (int off = 32; off > 0; off >>= 1) {
        sxx += __shfl_down(sxx, off);
        syy += __shfl_down(syy, off);
        szz += __shfl_down(szz, off);
        sxy += __shfl_down(sxy, off);
        sxz += __shfl_down(sxz, off);
        syz += __shfl_down(syz, off);
    }

    __shared__ float red[TPB / 64][6];
    const int wave = threadIdx.x >> 6;
    const int lane = threadIdx.x & 63;
    if (lane == 0) {
        red[wave][0] = sxx; red[wave][1] = syy; red[wave][2] = szz;
        red[wave][3] = sxy; red[wave][4] = sxz; red[wave][5] = syz;
    }
    __syncthreads();
    if (threadIdx.x < 6) {
        float s = 0.f;
        for (int w = 0; w < TPB / 64; ++w) s += red[w][threadIdx.x];
        // transposed: [b][k][BPB]
        partials[((size_t)b * 6 + threadIdx.x) * BPB + blockIdx.x] = s;
    }
}

__device__ inline void quat_to_rot_dev(float x, float y, float z, float w, float R[3][3]) {
    float inv = rsqrtf(x * x + y * y + z * z + w * w);
    x *= inv; y *= inv; z *= inv; w *= inv;
    const float xx = x * x, yy = y * y, zz = z * z;
    const float xy = x * y, xz = x * z, yz = y * z;
    const float wx = w * x, wy = w * y, wz = w * z;
    R[0][0] = 1.f - 2.f * (yy + zz); R[0][1] = 2.f * (xy - wz);       R[0][2] = 2.f * (xz + wy);
    R[1][0] = 2.f * (xy + wz);       R[1][1] = 1.f - 2.f * (xx + zz); R[1][2] = 2.f * (yz - wx);
    R[2][0] = 2.f * (xz - wy);       R[2][1] = 2.f * (yz + wx);       R[2][2] = 1.f - 2.f * (xx + yy);
}

__global__ __launch_bounds__(256) void finalize_kernel(
        const float* __restrict__ predquat,
        const float* __restrict__ gtquat,
        const float* __restrict__ partials,
        float* __restrict__ out, int B) {
    __shared__ float smom[32][6];
    const int t = threadIdx.x;
    // stage 1: lanes 0..191 each reduce one (batch, component): 32 contiguous floats
    if (t < B * 6) {
        const int bb = t / 6, k = t % 6;
        const vf4* p = (const vf4*)&partials[((size_t)bb * 6 + k) * BPB];
        float s = 0.f;
        #pragma unroll
        for (int j = 0; j < BPB / 4; ++j) {
            const vf4 v = p[j];
            s += v.x + v.y + v.z + v.w;
        }
        smom[bb][k] = s;
    }
    __syncthreads();
    if (t >= 64) return;

    float val = 0.f;
    if (t < B) {
        const float* m = smom[t];
        const float M[3][3] = {{m[0], m[3], m[4]},
                               {m[3], m[1], m[5]},
                               {m[4], m[5], m[2]}};
        float P[3][3], G[3][3];
        quat_to_rot_dev(predquat[4 * t], predquat[4 * t + 1], predquat[4 * t + 2], predquat[4 * t + 3], P);
        quat_to_rot_dev(gtquat[4 * t], gtquat[4 * t + 1], gtquat[4 * t + 2], gtquat[4 * t + 3], G);

        // gg[j] = G_j M G_j^T
        float gg[3];
        for (int j = 0; j < 3; ++j) {
            const float t0 = G[j][0] * M[0][0] + G[j][1] * M[1][0] + G[j][2] * M[2][0];
            const float t1 = G[j][0] * M[0][1] + G[j][1] * M[1][1] + G[j][2] * M[2][1];
            const float t2 = G[j][0] * M[0][2] + G[j][1] * M[1][2] + G[j][2] * M[2][2];
            gg[j] = t0 * G[j][0] + t1 * G[j][1] + t2 * G[j][2];
        }
        // pp[i] = P_i M P_i^T ; cr[i][j] = P_i M G_j^T
        float pp[3], cr[3][3];
        for (int i = 0; i < 3; ++i) {
            const float t0 = P[i][0] * M[0][0] + P[i][1] * M[1][0] + P[i][2] * M[2][0];
            const float t1 = P[i][0] * M[0][1] + P[i][1] * M[1][1] + P[i][2] * M[2][1];
            const float t2 = P[i][0] * M[0][2] + P[i][1] * M[1][2] + P[i][2] * M[2][2];
            pp[i] = t0 * P[i][0] + t1 * P[i][1] + t2 * P[i][2];
            for (int j = 0; j < 3; ++j)
                cr[i][j] = t0 * G[j][0] + t1 * G[j][1] + t2 * G[j][2];
        }
        float acc = 0.f;
        for (int j = 0; j < 3; ++j) {
            const float d0 = gg[j] + pp[0] - 2.f * cr[0][j];
            const float d1 = gg[j] + pp[1] - 2.f * cr[1][j];
            const float d2 = gg[j] + pp[2] - 2.f * cr[2][j];
            acc += fminf(d0, fminf(d1, d2));
        }
        val = acc / 3.f;
    }
    // wave reduce sum across 64 lanes (wave 0 only; others returned)
    for (int off = 32; off > 0; off >>= 1) val += __shfl_down(val, off);
    if (t == 0) out[0] = val / (float)B;
}

extern "C" void kernel_launch(void* const* d_in, const int* in_sizes, int n_in,
                              void* d_out, int out_size, void* d_ws, size_t ws_size,
                              hipStream_t stream) {
    const float* predquat = (const float*)d_in[0];
    const float* gtquat   = (const float*)d_in[1];
    const float* points   = (const float*)d_in[2];
    float* out = (float*)d_out;
    float* partials = (float*)d_ws;  // B * 6 * BPB floats = 24 KB

    const int B = in_sizes[0] / 4;           // 32
    const int N = in_sizes[2] / (B * 3);     // 262144

    dim3 grid(BPB, B);
    const int n4 = N >> 2;
    const int stride = BPB * TPB;
    if (n4 == 8 * stride) {
        moments_kernel<8><<<grid, TPB, 0, stream>>>(points, partials, N);
    } else {
        moments_kernel<0><<<grid, TPB, 0, stream>>>(points, partials, N);
    }
    finalize_kernel<<<1, 256, 0, stream>>>(predquat, gtquat, partials, out, B);
}